// Round 2
// baseline (277.104 us; speedup 1.0000x reference)
//
#include <hip/hip_runtime.h>
#include <hip/hip_bf16.h>
#include <math.h>

typedef __attribute__((ext_vector_type(8))) short short8;
typedef __attribute__((ext_vector_type(4))) float f32x4;

// round-to-nearest-even f32 -> bf16 (bit trick; inputs are finite normals)
static __device__ __forceinline__ short f2bf(float f) {
  union { float f; unsigned u; } x;
  x.f = f;
  unsigned r = x.u + 0x7fffu + ((x.u >> 16) & 1u);
  return (short)(r >> 16);
}

__global__ __launch_bounds__(256) void cvt_f32_bf16(const float* __restrict__ in,
                                                    short* __restrict__ out, int n8) {
  int i = blockIdx.x * 256 + threadIdx.x;
  if (i >= n8) return;
  const float4* p = (const float4*)in + (size_t)i * 2;
  float4 a = p[0], b = p[1];
  short8 o;
  o[0] = f2bf(a.x); o[1] = f2bf(a.y); o[2] = f2bf(a.z); o[3] = f2bf(a.w);
  o[4] = f2bf(b.x); o[5] = f2bf(b.y); o[6] = f2bf(b.z); o[7] = f2bf(b.w);
  *((short8*)out + i) = o;
}

// ---------------------------------------------------------------------------
// Generic C = A * B^T GEMM, bf16 MFMA 16x16x32, BM=BN=128, BK=32, 256 threads
// (4 waves, 2x2, each wave 64x64 = 4x4 fragments). A row-major MxK, Bt row-
// major NxK (both lda=ldb=K). Epilogue selected by MODE:
//   0: C row-major bf16 (projection Q/K)
//   1: C = V^T: write bf16 at [(b*N + col)*Cdim + (row % Cdim)] (projection V)
//   2: C fp32 = acc*scale + rel_bias[col-row+ml-1] (scores, per-batch z)
//   3: C fp32 = acc (PV output, per-batch z); A is fp32 (AF32=true)
// ---------------------------------------------------------------------------
constexpr int BM = 128, BN = 128, BK = 32, LDP = 40; // LDP: padded LDS row (bf16 elems)

template <int MODE, bool AF32>
__global__ __launch_bounds__(256) void gemm_bt(
    const void* __restrict__ Ab, const short* __restrict__ Btb,
    void* __restrict__ Cb, const float* __restrict__ rel_bias,
    int M, int N, int K, long aZ, long bZ, long cZ,
    int Cdim, float scale, int ml) {
  __shared__ short As[BM * LDP];
  __shared__ short Bs[BN * LDP];
  const int tid = threadIdx.x;
  const int z = blockIdx.z;
  const short* Abf = AF32 ? nullptr : ((const short*)Ab + (size_t)z * aZ);
  const float* Af = AF32 ? ((const float*)Ab + (size_t)z * aZ) : nullptr;
  const short* Bt = Btb + (size_t)z * bZ;
  const int brow = blockIdx.x * BM, bcol = blockIdx.y * BN;
  const int lane = tid & 63, wid = tid >> 6;
  const int wr = wid >> 1, wc = wid & 1;
  const int lrow = lane & 15, kg = lane >> 4;

  f32x4 acc[4][4] = {};

  for (int kk = 0; kk < K; kk += BK) {
    __syncthreads();
#pragma unroll
    for (int i = 0; i < 2; ++i) {
      int idx = tid + i * 256;       // 0..511
      int r = idx >> 2, c = (idx & 3) * 8;
      if constexpr (AF32) {
        const float* src = Af + (size_t)(brow + r) * K + kk + c;
        float4 f0 = *(const float4*)src;
        float4 f1 = *(const float4*)(src + 4);
        short8 o;
        o[0] = f2bf(f0.x); o[1] = f2bf(f0.y); o[2] = f2bf(f0.z); o[3] = f2bf(f0.w);
        o[4] = f2bf(f1.x); o[5] = f2bf(f1.y); o[6] = f2bf(f1.z); o[7] = f2bf(f1.w);
        *(short8*)&As[r * LDP + c] = o;
      } else {
        *(short8*)&As[r * LDP + c] =
            *(const short8*)(Abf + (size_t)(brow + r) * K + kk + c);
      }
      *(short8*)&Bs[r * LDP + c] =
          *(const short8*)(Bt + (size_t)(bcol + r) * K + kk + c);
    }
    __syncthreads();

    short8 a[4], b[4];
#pragma unroll
    for (int m = 0; m < 4; ++m)
      a[m] = *(const short8*)&As[(wr * 64 + m * 16 + lrow) * LDP + kg * 8];
#pragma unroll
    for (int n = 0; n < 4; ++n)
      b[n] = *(const short8*)&Bs[(wc * 64 + n * 16 + lrow) * LDP + kg * 8];
#pragma unroll
    for (int m = 0; m < 4; ++m)
#pragma unroll
      for (int n = 0; n < 4; ++n)
        acc[m][n] = __builtin_amdgcn_mfma_f32_16x16x32_bf16(a[m], b[n], acc[m][n], 0, 0, 0);
  }

#pragma unroll
  for (int m = 0; m < 4; ++m) {
#pragma unroll
    for (int n = 0; n < 4; ++n) {
#pragma unroll
      for (int r = 0; r < 4; ++r) {
        float v = acc[m][n][r];
        int gr = brow + wr * 64 + m * 16 + kg * 4 + r;
        int gc = bcol + wc * 64 + n * 16 + lrow;
        if constexpr (MODE == 0) {
          ((short*)Cb)[(size_t)gr * N + gc] = f2bf(v);
        } else if constexpr (MODE == 1) {
          int b_ = gr / Cdim, c_ = gr % Cdim;
          ((short*)Cb)[((size_t)b_ * N + gc) * Cdim + c_] = f2bf(v);
        } else if constexpr (MODE == 2) {
          int idx = gc - gr + (ml - 1);
          idx = min(max(idx, 0), 2 * ml - 2);
          ((float*)Cb + (size_t)z * cZ)[(size_t)gr * N + gc] = v * scale + rel_bias[idx];
        } else {
          ((float*)Cb + (size_t)z * cZ)[(size_t)gr * N + gc] = v;
        }
      }
    }
  }
}

// Row softmax in place over rows of length 2048 (one block per row).
__global__ __launch_bounds__(256) void softmax_rows(float* __restrict__ w, int Cd) {
  const size_t row = blockIdx.x;
  float4* p = (float4*)(w + row * (size_t)Cd);
  const int tid = threadIdx.x;
  float4 v0 = p[tid];
  float4 v1 = p[tid + 256];
  float mx = fmaxf(fmaxf(fmaxf(v0.x, v0.y), fmaxf(v0.z, v0.w)),
                   fmaxf(fmaxf(v1.x, v1.y), fmaxf(v1.z, v1.w)));
#pragma unroll
  for (int o = 32; o; o >>= 1) mx = fmaxf(mx, __shfl_xor(mx, o));
  __shared__ float red[8];
  const int wv = tid >> 6;
  if ((tid & 63) == 0) red[wv] = mx;
  __syncthreads();
  mx = fmaxf(fmaxf(red[0], red[1]), fmaxf(red[2], red[3]));
  v0.x = __expf(v0.x - mx); v0.y = __expf(v0.y - mx);
  v0.z = __expf(v0.z - mx); v0.w = __expf(v0.w - mx);
  v1.x = __expf(v1.x - mx); v1.y = __expf(v1.y - mx);
  v1.z = __expf(v1.z - mx); v1.w = __expf(v1.w - mx);
  float s = v0.x + v0.y + v0.z + v0.w + v1.x + v1.y + v1.z + v1.w;
#pragma unroll
  for (int o = 32; o; o >>= 1) s += __shfl_xor(s, o);
  if ((tid & 63) == 0) red[4 + wv] = s;
  __syncthreads();
  s = red[4] + red[5] + red[6] + red[7];
  float inv = 1.0f / s;
  v0.x *= inv; v0.y *= inv; v0.z *= inv; v0.w *= inv;
  v1.x *= inv; v1.y *= inv; v1.z *= inv; v1.w *= inv;
  p[tid] = v0;
  p[tid + 256] = v1;
}

extern "C" void kernel_launch(void* const* d_in, const int* in_sizes, int n_in,
                              void* d_out, int out_size, void* d_ws, size_t ws_size,
                              hipStream_t stream) {
  const float* x = (const float*)d_in[0];
  const float* Wq = (const float*)d_in[1];
  const float* Wk = (const float*)d_in[2];
  const float* Wv = (const float*)d_in[3];
  const float* rb = (const float*)d_in[4];

  const int E = 1024;                       // W is E x E (in_sizes[1] = 1048576)
  const int Mt = in_sizes[0] / E;           // B*C = 8192
  const int Cd = out_size / Mt - E;         // 2048
  const int B = Mt / Cd;                    // 4
  const int ml = (in_sizes[4] + 1) / 2;     // max_len = 2048
  const float scale = 1.0f / sqrtf((float)E);

  // workspace layout (bf16 = short), 70 MB total
  short* xb = (short*)d_ws;                 // Mt*E
  short* wqb = xb + (size_t)Mt * E;         // E*E
  short* wkb = wqb + (size_t)E * E;
  short* wvb = wkb + (size_t)E * E;
  short* Qb = wvb + (size_t)E * E;          // Mt*E
  short* Kb = Qb + (size_t)Mt * E;          // Mt*E
  short* Vt = Kb + (size_t)Mt * E;          // B*E*Cd = Mt*E

  float* outp = (float*)d_out;              // Mt*E floats
  float* wts = outp + (size_t)Mt * E;       // Mt*Cd floats

  // casts
  cvt_f32_bf16<<<(Mt * E) / 2048, 256, 0, stream>>>(x, xb, (Mt * E) / 8);
  cvt_f32_bf16<<<(E * E) / 2048, 256, 0, stream>>>(Wq, wqb, (E * E) / 8);
  cvt_f32_bf16<<<(E * E) / 2048, 256, 0, stream>>>(Wk, wkb, (E * E) / 8);
  cvt_f32_bf16<<<(E * E) / 2048, 256, 0, stream>>>(Wv, wvb, (E * E) / 8);

  dim3 blk(256);
  // projections: Q = x Wq^T, K = x Wk^T, V^T
  gemm_bt<0, false><<<dim3(Mt / 128, E / 128, 1), blk, 0, stream>>>(
      xb, wqb, Qb, nullptr, Mt, E, E, 0, 0, 0, Cd, 0.f, ml);
  gemm_bt<0, false><<<dim3(Mt / 128, E / 128, 1), blk, 0, stream>>>(
      xb, wkb, Kb, nullptr, Mt, E, E, 0, 0, 0, Cd, 0.f, ml);
  gemm_bt<1, false><<<dim3(Mt / 128, E / 128, 1), blk, 0, stream>>>(
      xb, wvb, Vt, nullptr, Mt, E, E, 0, 0, 0, Cd, 0.f, ml);
  // scores = Q K^T * scale + bias  (into weights output region, fp32)
  gemm_bt<2, false><<<dim3(Cd / 128, Cd / 128, B), blk, 0, stream>>>(
      Qb, Kb, wts, rb, Cd, Cd, E, (long)Cd * E, (long)Cd * E, (long)Cd * Cd,
      Cd, scale, ml);
  // softmax rows in place
  softmax_rows<<<Mt, 256, 0, stream>>>(wts, Cd);
  // out = weights @ V  (A fp32 staged->bf16, Bt = V^T)
  gemm_bt<3, true><<<dim3(Cd / 128, E / 128, B), blk, 0, stream>>>(
      wts, Vt, outp, nullptr, Cd, E, Cd, (long)Cd * Cd, (long)E * Cd,
      (long)Cd * E, Cd, 0.f, ml);
}

// Round 3
// 263.845 us; speedup vs baseline: 1.0503x; 1.0503x over previous
//
#include <hip/hip_runtime.h>
#include <hip/hip_bf16.h>
#include <math.h>

typedef __attribute__((ext_vector_type(8))) short short8;
typedef __attribute__((ext_vector_type(4))) short short4v;
typedef __attribute__((ext_vector_type(4))) float f32x4;

// round-to-nearest-even f32 -> bf16
static __device__ __forceinline__ short f2bf(float f) {
  union { float f; unsigned u; } x;
  x.f = f;
  unsigned r = x.u + 0x7fffu + ((x.u >> 16) & 1u);
  return (short)(r >> 16);
}

// direct global->LDS copy, 16 B per lane; LDS base must be wave-uniform
#define GLOAD_LDS16(g, l)                                              \
  __builtin_amdgcn_global_load_lds(                                    \
      (const __attribute__((address_space(1))) void*)(g),              \
      (__attribute__((address_space(3))) void*)(l), 16, 0, 0)

__global__ __launch_bounds__(256) void cvt_f32_bf16(const float* __restrict__ in,
                                                    short* __restrict__ out, int n8) {
  int i = blockIdx.x * 256 + threadIdx.x;
  if (i >= n8) return;
  const float4* p = (const float4*)in + (size_t)i * 2;
  float4 a = p[0], b = p[1];
  short8 o;
  o[0] = f2bf(a.x); o[1] = f2bf(a.y); o[2] = f2bf(a.z); o[3] = f2bf(a.w);
  o[4] = f2bf(b.x); o[5] = f2bf(b.y); o[6] = f2bf(b.z); o[7] = f2bf(b.w);
  *((short8*)out + i) = o;
}

// ---------------------------------------------------------------------------
// C = A * B^T, bf16 MFMA 16x16x32. BM=BN=128, BK=32, 256 threads (4 waves 2x2,
// each wave 64x64 = 4x4 fragments). m97 structure: linear LDS [128][32],
// global_load_lds width-16 staging, 2 barriers per K-step.
// MODE 0: C bf16 row-major        MODE 1: C bf16 V^T scatter
// MODE 2: C fp32 = acc*scale + rel_bias[gc-gr+ml-1]   MODE 3: C fp32 = acc
// ---------------------------------------------------------------------------
template <int MODE>
__global__ __launch_bounds__(256) void gemm_bt(
    const short* __restrict__ A, const short* __restrict__ Btb,
    void* __restrict__ Cb, const float* __restrict__ rel_bias,
    int M, int N, int K, long aZ, long bZ, long cZ,
    int Cdim, float scale, int ml) {
  __shared__ short As[128 * 32];
  __shared__ short Bs[128 * 32];
  const int tid = threadIdx.x;
  const int z = blockIdx.z;
  const short* Az = A + (size_t)z * aZ;
  const short* Bt = Btb + (size_t)z * bZ;
  const int brow = blockIdx.x * 128, bcol = blockIdx.y * 128;
  const int lane = tid & 63, wid = tid >> 6;
  const int wr = wid >> 1, wc = wid & 1;
  const int lrow = lane & 15, kg = lane >> 4;

  f32x4 acc[4][4] = {};

  for (int kk = 0; kk < K; kk += 32) {
    __syncthreads();
    // stage A and B tiles (8 KB each) via direct-to-LDS; each wave covers
    // 2x 1024 B per tile. LDS layout linear: byte = row*64 + col*2.
#pragma unroll
    for (int l = 0; l < 2; ++l) {
      const int base = wid * 2048 + l * 1024;      // wave-uniform byte base
      const int off = base + lane * 16;            // this lane's 16 B
      const int r = off >> 6, c = (off & 63) >> 1;
      GLOAD_LDS16(Az + (size_t)(brow + r) * K + kk + c, &As[base >> 1]);
      GLOAD_LDS16(Bt + (size_t)(bcol + r) * K + kk + c, &Bs[base >> 1]);
    }
    __syncthreads();

    short8 a[4], b[4];
#pragma unroll
    for (int m = 0; m < 4; ++m)
      a[m] = *(const short8*)&As[(wr * 64 + m * 16 + lrow) * 32 + kg * 8];
#pragma unroll
    for (int n = 0; n < 4; ++n)
      b[n] = *(const short8*)&Bs[(wc * 64 + n * 16 + lrow) * 32 + kg * 8];
#pragma unroll
    for (int m = 0; m < 4; ++m)
#pragma unroll
      for (int n = 0; n < 4; ++n)
        acc[m][n] = __builtin_amdgcn_mfma_f32_16x16x32_bf16(a[m], b[n], acc[m][n], 0, 0, 0);
  }

#pragma unroll
  for (int m = 0; m < 4; ++m) {
#pragma unroll
    for (int n = 0; n < 4; ++n) {
#pragma unroll
      for (int r = 0; r < 4; ++r) {
        float v = acc[m][n][r];
        int gr = brow + wr * 64 + m * 16 + kg * 4 + r;
        int gc = bcol + wc * 64 + n * 16 + lrow;
        if constexpr (MODE == 0) {
          ((short*)Cb)[(size_t)gr * N + gc] = f2bf(v);
        } else if constexpr (MODE == 1) {
          int b_ = gr / Cdim, c_ = gr % Cdim;
          ((short*)Cb)[((size_t)b_ * N + gc) * Cdim + c_] = f2bf(v);
        } else if constexpr (MODE == 2) {
          int idx = gc - gr + (ml - 1);
          idx = min(max(idx, 0), 2 * ml - 2);
          ((float*)Cb + (size_t)z * cZ)[(size_t)gr * N + gc] = v * scale + rel_bias[idx];
        } else {
          ((float*)Cb + (size_t)z * cZ)[(size_t)gr * N + gc] = v;
        }
      }
    }
  }
}

// Row softmax in place (rows of 2048) + bf16 copy for the PV GEMM.
__global__ __launch_bounds__(256) void softmax_rows(float* __restrict__ w,
                                                    short* __restrict__ wb, int Cd) {
  const size_t row = blockIdx.x;
  float4* p = (float4*)(w + row * (size_t)Cd);
  const int tid = threadIdx.x;
  float4 v0 = p[tid];
  float4 v1 = p[tid + 256];
  float mx = fmaxf(fmaxf(fmaxf(v0.x, v0.y), fmaxf(v0.z, v0.w)),
                   fmaxf(fmaxf(v1.x, v1.y), fmaxf(v1.z, v1.w)));
#pragma unroll
  for (int o = 32; o; o >>= 1) mx = fmaxf(mx, __shfl_xor(mx, o));
  __shared__ float red[8];
  const int wv = tid >> 6;
  if ((tid & 63) == 0) red[wv] = mx;
  __syncthreads();
  mx = fmaxf(fmaxf(red[0], red[1]), fmaxf(red[2], red[3]));
  v0.x = __expf(v0.x - mx); v0.y = __expf(v0.y - mx);
  v0.z = __expf(v0.z - mx); v0.w = __expf(v0.w - mx);
  v1.x = __expf(v1.x - mx); v1.y = __expf(v1.y - mx);
  v1.z = __expf(v1.z - mx); v1.w = __expf(v1.w - mx);
  float s = v0.x + v0.y + v0.z + v0.w + v1.x + v1.y + v1.z + v1.w;
#pragma unroll
  for (int o = 32; o; o >>= 1) s += __shfl_xor(s, o);
  if ((tid & 63) == 0) red[4 + wv] = s;
  __syncthreads();
  s = red[4] + red[5] + red[6] + red[7];
  float inv = 1.0f / s;
  v0.x *= inv; v0.y *= inv; v0.z *= inv; v0.w *= inv;
  v1.x *= inv; v1.y *= inv; v1.z *= inv; v1.w *= inv;
  p[tid] = v0;
  p[tid + 256] = v1;
  short4v b0, b1;
  b0[0] = f2bf(v0.x); b0[1] = f2bf(v0.y); b0[2] = f2bf(v0.z); b0[3] = f2bf(v0.w);
  b1[0] = f2bf(v1.x); b1[1] = f2bf(v1.y); b1[2] = f2bf(v1.z); b1[3] = f2bf(v1.w);
  short* wrow = wb + row * (size_t)Cd;
  *(short4v*)&wrow[tid * 4] = b0;
  *(short4v*)&wrow[1024 + tid * 4] = b1;
}

extern "C" void kernel_launch(void* const* d_in, const int* in_sizes, int n_in,
                              void* d_out, int out_size, void* d_ws, size_t ws_size,
                              hipStream_t stream) {
  const float* x = (const float*)d_in[0];
  const float* Wq = (const float*)d_in[1];
  const float* Wk = (const float*)d_in[2];
  const float* Wv = (const float*)d_in[3];
  const float* rb = (const float*)d_in[4];

  const int E = 1024;
  const int Mt = in_sizes[0] / E;           // B*C = 8192
  const int Cd = out_size / Mt - E;         // 2048
  const int B = Mt / Cd;                    // 4
  const int ml = (in_sizes[4] + 1) / 2;     // max_len = 2048
  const float scale = 1.0f / sqrtf((float)E);

  // workspace layout (bf16 = short), 70 MB total
  short* xb = (short*)d_ws;                 // Mt*E
  short* wqb = xb + (size_t)Mt * E;         // E*E
  short* wkb = wqb + (size_t)E * E;
  short* wvb = wkb + (size_t)E * E;
  short* Qb = wvb + (size_t)E * E;          // Mt*E
  short* Kb = Qb + (size_t)Mt * E;          // Mt*E
  short* Vt = Kb + (size_t)Mt * E;          // B*E*Cd = Mt*E
  // bf16 softmax weights: reuse Qb+Kb region (32 MB, dead after scores GEMM)
  short* wbf = Qb;                          // Mt*Cd

  float* outp = (float*)d_out;              // Mt*E floats
  float* wts = outp + (size_t)Mt * E;       // Mt*Cd floats

  cvt_f32_bf16<<<(Mt * E) / 2048, 256, 0, stream>>>(x, xb, (Mt * E) / 8);
  cvt_f32_bf16<<<(E * E) / 2048, 256, 0, stream>>>(Wq, wqb, (E * E) / 8);
  cvt_f32_bf16<<<(E * E) / 2048, 256, 0, stream>>>(Wk, wkb, (E * E) / 8);
  cvt_f32_bf16<<<(E * E) / 2048, 256, 0, stream>>>(Wv, wvb, (E * E) / 8);

  dim3 blk(256);
  gemm_bt<0><<<dim3(Mt / 128, E / 128, 1), blk, 0, stream>>>(
      xb, wqb, Qb, nullptr, Mt, E, E, 0, 0, 0, Cd, 0.f, ml);
  gemm_bt<0><<<dim3(Mt / 128, E / 128, 1), blk, 0, stream>>>(
      xb, wkb, Kb, nullptr, Mt, E, E, 0, 0, 0, Cd, 0.f, ml);
  gemm_bt<1><<<dim3(Mt / 128, E / 128, 1), blk, 0, stream>>>(
      xb, wvb, Vt, nullptr, Mt, E, E, 0, 0, 0, Cd, 0.f, ml);
  gemm_bt<2><<<dim3(Cd / 128, Cd / 128, B), blk, 0, stream>>>(
      Qb, Kb, wts, rb, Cd, Cd, E, (long)Cd * E, (long)Cd * E, (long)Cd * Cd,
      Cd, scale, ml);
  softmax_rows<<<Mt, 256, 0, stream>>>(wts, wbf, Cd);
  gemm_bt<3><<<dim3(Cd / 128, E / 128, B), blk, 0, stream>>>(
      wbf, Vt, outp, nullptr, Cd, E, Cd, (long)Cd * Cd, (long)E * Cd,
      (long)Cd * E, Cd, 0.f, ml);
}

// Round 5
// 214.228 us; speedup vs baseline: 1.2935x; 1.2316x over previous
//
#include <hip/hip_runtime.h>
#include <hip/hip_bf16.h>
#include <math.h>

typedef __attribute__((ext_vector_type(8))) short short8;
typedef __attribute__((ext_vector_type(4))) short short4v;
typedef __attribute__((ext_vector_type(4))) float f32x4;

// round-to-nearest-even f32 -> bf16
static __device__ __forceinline__ short f2bf(float f) {
  union { float f; unsigned u; } x;
  x.f = f;
  unsigned r = x.u + 0x7fffu + ((x.u >> 16) & 1u);
  return (short)(r >> 16);
}

// direct global->LDS, 16 B/lane; LDS base wave-uniform, global src per-lane
#define GLD16(g, l)                                                   \
  __builtin_amdgcn_global_load_lds(                                   \
      (const __attribute__((address_space(1))) void*)(g),             \
      (__attribute__((address_space(3))) void*)(l), 16, 0, 0)
#define BAR() asm volatile("s_barrier" ::: "memory")
#define VMCNT3() asm volatile("s_waitcnt vmcnt(3)" ::: "memory")
#define VMCNT0() asm volatile("s_waitcnt vmcnt(0)" ::: "memory")

__global__ __launch_bounds__(256) void cvt_f32_bf16(const float* __restrict__ in,
                                                    short* __restrict__ out, int n8) {
  int i = blockIdx.x * 256 + threadIdx.x;
  if (i >= n8) return;
  const float4* p = (const float4*)in + (size_t)i * 2;
  float4 a = p[0], b = p[1];
  short8 o;
  o[0] = f2bf(a.x); o[1] = f2bf(a.y); o[2] = f2bf(a.z); o[3] = f2bf(a.w);
  o[4] = f2bf(b.x); o[5] = f2bf(b.y); o[6] = f2bf(b.z); o[7] = f2bf(b.w);
  *((short8*)out + i) = o;
}

// ---------------------------------------------------------------------------
// C = A * B^T, bf16 MFMA 16x16x32. BM=256, BN=128, BK=64, 512 threads
// (8 waves 2M x 4N, wave tile 128x32, M_rep=8, N_rep=2). Double-buffered LDS
// (96 KB), 4 phases per 2 K-tiles, counted vmcnt(3) once per K-tile (never 0
// in main loop), T2 XOR swizzle (pre-swizzled global src + swizzled ds_read),
// setprio around the 16-MFMA cluster.
// MODE 2: C fp32 = acc*scale + rel_bias[gc-gr+ml-1] (scores)
// MODE 3: C fp32 = acc (PV)
// MODE 4: fused QKV: slice 0 -> Q bf16, 1 -> K bf16, 2 -> V^T bf16 scatter
// ---------------------------------------------------------------------------
template <int MODE>
__global__ __launch_bounds__(512) void gemm8p(
    const short* __restrict__ A, const short* __restrict__ Bt,
    void* __restrict__ C0, void* __restrict__ C1, void* __restrict__ C2,
    const float* __restrict__ rel_bias,
    int N, int K, long aZ, long bZ, long cZ, int Cdim, float scale, int ml) {
  __shared__ short sA[2][256 * 64];
  __shared__ short sB[2][128 * 64];
  const int tid = threadIdx.x, lane = tid & 63, wid = tid >> 6;
  const int z = blockIdx.z;
  const short* Az = A + (size_t)z * aZ;
  const short* Bz = Bt + (size_t)z * bZ;
  const int brow = blockIdx.x * 256, bcol = blockIdx.y * 128;
  const int wr = wid >> 2, wc = wid & 3;
  const int lrow = lane & 15, kg = lane >> 4;
  const int l8 = lane >> 3, lm8 = lane & 7;
  const int scol = (lm8 ^ l8) * 8;  // pre-swizzled source col (elems)

  // stage source bases (per-lane) and LDS dest bases (wave-uniform, shorts)
  const short* aS[2][2];
  int aD[2][2];
#pragma unroll
  for (int h = 0; h < 2; ++h)
#pragma unroll
    for (int j = 0; j < 2; ++j) {
      int c = wid * 2 + j;
      int rb = c * 8 + (c >= 8 ? 64 : 0) + h * 64;
      aS[h][j] = Az + (size_t)(brow + rb + l8) * K + scol;
      aD[h][j] = rb * 64;
    }
  const short* bS[2];
  int bD[2];
#pragma unroll
  for (int h = 0; h < 2; ++h) {
    int rb = wid * 8 + h * 64;
    bS[h] = Bz + (size_t)(bcol + rb + l8) * K + scol;
    bD[h] = rb * 64;
  }

  // ds_read bases: swizzled slot offsets (shorts)
  const int sks0 = ((0 + kg) ^ (lrow & 7)) * 8;
  const int sks1 = ((4 + kg) ^ (lrow & 7)) * 8;
  const int aR = (wr * 128 + lrow) * 64;  // + MH*4096 + mq*1024 + sks
  const int bR = (wc * 32 + lrow) * 64;   // + nq*1024 + sks

  short8 a[4][2], b[2][2];
  f32x4 acc[8][2] = {};

#define STG_A(BUF, H, T)                                          \
  do {                                                            \
    GLD16(aS[H][0] + (size_t)(T) * 64, &sA[BUF][aD[H][0]]);       \
    GLD16(aS[H][1] + (size_t)(T) * 64, &sA[BUF][aD[H][1]]);       \
  } while (0)
#define STG_B(BUF, H, T) GLD16(bS[H] + (size_t)(T) * 64, &sB[BUF][bD[H]])
#define RD_A(BUF, MH)                                                         \
  do {                                                                        \
    _Pragma("unroll") for (int mq = 0; mq < 4; ++mq) {                        \
      a[mq][0] = *(const short8*)&sA[BUF][aR + (MH)*4096 + mq * 1024 + sks0]; \
      a[mq][1] = *(const short8*)&sA[BUF][aR + (MH)*4096 + mq * 1024 + sks1]; \
    }                                                                         \
  } while (0)
#define RD_B(BUF)                                                  \
  do {                                                             \
    _Pragma("unroll") for (int nq = 0; nq < 2; ++nq) {             \
      b[nq][0] = *(const short8*)&sB[BUF][bR + nq * 1024 + sks0];  \
      b[nq][1] = *(const short8*)&sB[BUF][bR + nq * 1024 + sks1];  \
    }                                                              \
  } while (0)
#define MFMA16(MH)                                                            \
  do {                                                                        \
    __builtin_amdgcn_s_setprio(1);                                            \
    _Pragma("unroll") for (int mq = 0; mq < 4; ++mq)                          \
        _Pragma("unroll") for (int nq = 0; nq < 2; ++nq) {                    \
      acc[(MH)*4 + mq][nq] = __builtin_amdgcn_mfma_f32_16x16x32_bf16(         \
          a[mq][0], b[nq][0], acc[(MH)*4 + mq][nq], 0, 0, 0);                 \
      acc[(MH)*4 + mq][nq] = __builtin_amdgcn_mfma_f32_16x16x32_bf16(         \
          a[mq][1], b[nq][1], acc[(MH)*4 + mq][nq], 0, 0, 0);                 \
    }                                                                         \
    __builtin_amdgcn_s_setprio(0);                                            \
  } while (0)

  // prologue: tile0 -> buf0 (6 loads), tile1 partial {Ah0,Ba} -> buf1 (3)
  STG_A(0, 0, 0); STG_B(0, 0, 0); STG_A(0, 1, 0); STG_B(0, 1, 0);
  STG_A(1, 0, 1); STG_B(1, 0, 1);
  VMCNT3();
  BAR();

  const int NIT = K >> 7;  // K/128, >= 8 here
  for (int i = 0; i < NIT - 1; ++i) {
    const int t1 = 2 * i + 1, t2 = 2 * i + 2, t3 = 2 * i + 3;
    // ph0: read buf0 {Ah0, B}; stage buf1 tile t1 {Ah1, Bb}
    RD_A(0, 0); RD_B(0);
    STG_A(1, 1, t1); STG_B(1, 1, t1);
    BAR();
    MFMA16(0);
    BAR();
    // ph1: read buf0 {Ah1}; stage buf0 tile t2 {Ah0, Ba}
    RD_A(0, 1);
    STG_A(0, 0, t2); STG_B(0, 0, t2);
    BAR();
    MFMA16(1);
    VMCNT3();   // buf1 (tile t1) complete through ph0; ph1's 3 in flight
    BAR();
    // ph2: read buf1 {Ah0, B}; stage buf0 tile t2 {Ah1, Bb}
    RD_A(1, 0); RD_B(1);
    STG_A(0, 1, t2); STG_B(0, 1, t2);
    BAR();
    MFMA16(0);
    BAR();
    // ph3: read buf1 {Ah1}; stage buf1 tile t3 {Ah0, Ba}
    RD_A(1, 1);
    STG_A(1, 0, t3); STG_B(1, 0, t3);
    BAR();
    MFMA16(1);
    VMCNT3();   // buf0 (tile t2) complete through ph2; ph3's 3 in flight
    BAR();
  }
  // final iteration: ph0 completes buf1 (tile 2*NIT-1); no further stages
  {
    const int t1 = 2 * (NIT - 1) + 1;
    RD_A(0, 0); RD_B(0);
    STG_A(1, 1, t1); STG_B(1, 1, t1);
    BAR(); MFMA16(0); BAR();
    RD_A(0, 1);
    BAR(); MFMA16(1);
    VMCNT0();   // tail drain: nothing issued after ph0's stages
    BAR();
    RD_A(1, 0); RD_B(1);
    BAR(); MFMA16(0); BAR();
    RD_A(1, 1);
    BAR(); MFMA16(1);
  }

  // epilogue
#pragma unroll
  for (int m = 0; m < 8; ++m) {
#pragma unroll
    for (int n = 0; n < 2; ++n) {
#pragma unroll
      for (int r = 0; r < 4; ++r) {
        float v = acc[m][n][r];
        int gr = brow + wr * 128 + m * 16 + kg * 4 + r;
        int gc = bcol + wc * 32 + n * 16 + lrow;
        if constexpr (MODE == 2) {
          int idx = gc - gr + (ml - 1);
          idx = min(max(idx, 0), 2 * ml - 2);
          ((float*)C0 + (size_t)z * cZ)[(size_t)gr * N + gc] =
              v * scale + rel_bias[idx];
        } else if constexpr (MODE == 3) {
          ((float*)C0 + (size_t)z * cZ)[(size_t)gr * N + gc] = v;
        } else {  // MODE 4: fused QKV, E=1024 slices
          int s = gc >> 10, cc = gc & 1023;
          if (s == 0) {
            ((short*)C0)[(size_t)gr * 1024 + cc] = f2bf(v);
          } else if (s == 1) {
            ((short*)C1)[(size_t)gr * 1024 + cc] = f2bf(v);
          } else {
            int b_ = gr / Cdim, c_ = gr % Cdim;
            ((short*)C2)[((size_t)b_ * 1024 + cc) * Cdim + c_] = f2bf(v);
          }
        }
      }
    }
  }
#undef STG_A
#undef STG_B
#undef RD_A
#undef RD_B
#undef MFMA16
}

// Row softmax in place (rows of 2048) + bf16 copy for the PV GEMM.
__global__ __launch_bounds__(256) void softmax_rows(float* __restrict__ w,
                                                    short* __restrict__ wb, int Cd) {
  const size_t row = blockIdx.x;
  float4* p = (float4*)(w + row * (size_t)Cd);
  const int tid = threadIdx.x;
  float4 v0 = p[tid];
  float4 v1 = p[tid + 256];
  float mx = fmaxf(fmaxf(fmaxf(v0.x, v0.y), fmaxf(v0.z, v0.w)),
                   fmaxf(fmaxf(v1.x, v1.y), fmaxf(v1.z, v1.w)));
#pragma unroll
  for (int o = 32; o; o >>= 1) mx = fmaxf(mx, __shfl_xor(mx, o));
  __shared__ float red[8];
  const int wv = tid >> 6;
  if ((tid & 63) == 0) red[wv] = mx;
  __syncthreads();
  mx = fmaxf(fmaxf(red[0], red[1]), fmaxf(red[2], red[3]));
  v0.x = __expf(v0.x - mx); v0.y = __expf(v0.y - mx);
  v0.z = __expf(v0.z - mx); v0.w = __expf(v0.w - mx);
  v1.x = __expf(v1.x - mx); v1.y = __expf(v1.y - mx);
  v1.z = __expf(v1.z - mx); v1.w = __expf(v1.w - mx);
  float s = v0.x + v0.y + v0.z + v0.w + v1.x + v1.y + v1.z + v1.w;
#pragma unroll
  for (int o = 32; o; o >>= 1) s += __shfl_xor(s, o);
  if ((tid & 63) == 0) red[4 + wv] = s;
  __syncthreads();
  s = red[4] + red[5] + red[6] + red[7];
  float inv = 1.0f / s;
  v0.x *= inv; v0.y *= inv; v0.z *= inv; v0.w *= inv;
  v1.x *= inv; v1.y *= inv; v1.z *= inv; v1.w *= inv;
  p[tid] = v0;
  p[tid + 256] = v1;
  short4v b0, b1;
  b0[0] = f2bf(v0.x); b0[1] = f2bf(v0.y); b0[2] = f2bf(v0.z); b0[3] = f2bf(v0.w);
  b1[0] = f2bf(v1.x); b1[1] = f2bf(v1.y); b1[2] = f2bf(v1.z); b1[3] = f2bf(v1.w);
  short* wrow = wb + row * (size_t)Cd;
  *(short4v*)&wrow[tid * 4] = b0;
  *(short4v*)&wrow[1024 + tid * 4] = b1;
}

extern "C" void kernel_launch(void* const* d_in, const int* in_sizes, int n_in,
                              void* d_out, int out_size, void* d_ws, size_t ws_size,
                              hipStream_t stream) {
  const float* x = (const float*)d_in[0];
  const float* Wq = (const float*)d_in[1];
  const float* Wk = (const float*)d_in[2];
  const float* Wv = (const float*)d_in[3];
  const float* rb = (const float*)d_in[4];

  const int E = 1024;
  const int Mt = in_sizes[0] / E;           // B*C = 8192
  const int Cd = out_size / Mt - E;         // 2048
  const int B = Mt / Cd;                    // 4
  const int ml = (in_sizes[4] + 1) / 2;     // max_len = 2048
  const float scale = 1.0f / sqrtf((float)E);

  // workspace layout (bf16 = short)
  short* xb = (short*)d_ws;                 // Mt*E
  short* wqb = xb + (size_t)Mt * E;         // E*E (Wq,Wk,Wv contiguous = 3072xE)
  short* wkb = wqb + (size_t)E * E;
  short* wvb = wkb + (size_t)E * E;
  short* Qb = wvb + (size_t)E * E;          // Mt*E
  short* Kb = Qb + (size_t)Mt * E;          // Mt*E
  short* Vt = Kb + (size_t)Mt * E;          // B*E*Cd
  short* wbf = Qb;                          // Mt*Cd (reuse Q+K after scores)

  float* outp = (float*)d_out;              // Mt*E
  float* wts = outp + (size_t)Mt * E;       // Mt*Cd

  cvt_f32_bf16<<<(Mt * E) / 2048, 256, 0, stream>>>(x, xb, (Mt * E) / 8);
  cvt_f32_bf16<<<(E * E) / 2048, 256, 0, stream>>>(Wq, wqb, (E * E) / 8);
  cvt_f32_bf16<<<(E * E) / 2048, 256, 0, stream>>>(Wk, wkb, (E * E) / 8);
  cvt_f32_bf16<<<(E * E) / 2048, 256, 0, stream>>>(Wv, wvb, (E * E) / 8);

  dim3 blk(512);
  // fused QKV projection: A = xb (8192x1024), Bt = [Wq;Wk;Wv] (3072x1024)
  gemm8p<4><<<dim3(Mt / 256, 3 * E / 128, 1), blk, 0, stream>>>(
      xb, wqb, Qb, Kb, Vt, nullptr, 3 * E, E, 0, 0, 0, Cd, 0.f, ml);
  // scores = Q K^T * scale + bias (fp32 into weights region)
  gemm8p<2><<<dim3(Cd / 256, Cd / 128, B), blk, 0, stream>>>(
      Qb, Kb, wts, nullptr, nullptr, rb, Cd, E, (long)Cd * E, (long)Cd * E,
      (long)Cd * Cd, Cd, scale, ml);
  softmax_rows<<<Mt, 256, 0, stream>>>(wts, wbf, Cd);
  // out = weights @ V (A = bf16 weights, Bt = V^T)
  gemm8p<3><<<dim3(Cd / 256, E / 128, B), blk, 0, stream>>>(
      wbf, Vt, outp, nullptr, nullptr, nullptr, E, Cd, (long)Cd * Cd,
      (long)E * Cd, (long)Cd * E, Cd, 0.f, ml);
}

// Round 6
// 209.179 us; speedup vs baseline: 1.3247x; 1.0241x over previous
//
#include <hip/hip_runtime.h>
#include <hip/hip_bf16.h>
#include <math.h>

typedef __attribute__((ext_vector_type(8))) short short8;
typedef __attribute__((ext_vector_type(4))) short short4v;
typedef __attribute__((ext_vector_type(4))) float f32x4;

// round-to-nearest-even f32 -> bf16
static __device__ __forceinline__ short f2bf(float f) {
  union { float f; unsigned u; } x;
  x.f = f;
  unsigned r = x.u + 0x7fffu + ((x.u >> 16) & 1u);
  return (short)(r >> 16);
}

// direct global->LDS, 16 B/lane; LDS base wave-uniform, global src per-lane
#define GLD16(g, l)                                                   \
  __builtin_amdgcn_global_load_lds(                                   \
      (const __attribute__((address_space(1))) void*)(g),             \
      (__attribute__((address_space(3))) void*)(l), 16, 0, 0)
#define BAR() asm volatile("s_barrier" ::: "memory")
#define VMCNT6() asm volatile("s_waitcnt vmcnt(6)" ::: "memory")
#define VMCNT0() asm volatile("s_waitcnt vmcnt(0)" ::: "memory")

__global__ __launch_bounds__(256) void cvt_f32_bf16(const float* __restrict__ in,
                                                    short* __restrict__ out, int n8) {
  int i = blockIdx.x * 256 + threadIdx.x;
  if (i >= n8) return;
  const float4* p = (const float4*)in + (size_t)i * 2;
  float4 a = p[0], b = p[1];
  short8 o;
  o[0] = f2bf(a.x); o[1] = f2bf(a.y); o[2] = f2bf(a.z); o[3] = f2bf(a.w);
  o[4] = f2bf(b.x); o[5] = f2bf(b.y); o[6] = f2bf(b.z); o[7] = f2bf(b.w);
  *((short8*)out + i) = o;
}

// ---------------------------------------------------------------------------
// C = A * B^T, bf16 MFMA 16x16x32. BM=256, BN=128, BK=64, 512 threads
// (8 waves 2M x 4N, wave tile 128x32). TRIPLE-buffered LDS (144 KB): stage
// tile t+2 while computing tile t -> prefetch span ~4 sub-phases (~700+ cyc,
// covers HBM latency). vmcnt(6) once per K-tile (never 0 in main loop),
// T2 XOR swizzle (pre-swizzled global src + swizzled ds_read), setprio.
// MODE 2: C fp32 = acc*scale + rel_bias[gc-gr+ml-1] (scores)
// MODE 3: C fp32 = acc (PV)
// MODE 4: fused QKV: slice 0 -> Q bf16, 1 -> K bf16, 2 -> V^T bf16 scatter
// ---------------------------------------------------------------------------
template <int MODE>
__global__ __launch_bounds__(512) void gemm3b(
    const short* __restrict__ A, const short* __restrict__ Bt,
    void* __restrict__ C0, void* __restrict__ C1, void* __restrict__ C2,
    const float* __restrict__ rel_bias,
    int N, int K, long aZ, long bZ, long cZ, int Cdim, float scale, int ml) {
  __shared__ short sA[3][256 * 64];
  __shared__ short sB[3][128 * 64];
  const int tid = threadIdx.x, lane = tid & 63, wid = tid >> 6;
  const int z = blockIdx.z;
  const short* Az = A + (size_t)z * aZ;
  const short* Bz = Bt + (size_t)z * bZ;
  const int brow = blockIdx.x * 256, bcol = blockIdx.y * 128;
  const int wr = wid >> 2, wc = wid & 3;
  const int lrow = lane & 15, kg = lane >> 4;
  const int l8 = lane >> 3, lm8 = lane & 7;
  const int scol = (lm8 ^ l8) * 8;  // pre-swizzled source col (elems)

  // stage source bases (per-lane) and LDS dest offsets (wave-uniform, shorts)
  // A half h covers rows {0-63,128-191} (h=0) / {64-127,192-255} (h=1):
  // exactly the rows consumed by MFMA cluster MH=h for both wave-rows.
  const short* aS[2][2];
  int aD[2][2];
#pragma unroll
  for (int h = 0; h < 2; ++h)
#pragma unroll
    for (int j = 0; j < 2; ++j) {
      int c = wid * 2 + j;
      int rb = c * 8 + (c >= 8 ? 64 : 0) + h * 64;
      aS[h][j] = Az + (size_t)(brow + rb + l8) * K + scol;
      aD[h][j] = rb * 64;
    }
  const short* bS[2];
  int bD[2];
#pragma unroll
  for (int h = 0; h < 2; ++h) {
    int rb = wid * 8 + h * 64;
    bS[h] = Bz + (size_t)(bcol + rb + l8) * K + scol;
    bD[h] = rb * 64;
  }

  // ds_read bases: swizzled slot offsets (shorts)
  const int sks0 = ((0 + kg) ^ (lrow & 7)) * 8;
  const int sks1 = ((4 + kg) ^ (lrow & 7)) * 8;
  const int aR = (wr * 128 + lrow) * 64;  // + MH*4096 + mq*1024 + sks
  const int bR = (wc * 32 + lrow) * 64;   // + nq*1024 + sks

  short8 a[4][2], b[2][2];
  f32x4 acc[8][2] = {};

  // rotating buffer base pointers (register pointer swap, no runtime index)
  short *pa0 = &sA[0][0], *pa1 = &sA[1][0], *pa2 = &sA[2][0];
  short *pb0 = &sB[0][0], *pb1 = &sB[1][0], *pb2 = &sB[2][0];

#define STG_A(PA, H, T)                                          \
  do {                                                           \
    GLD16(aS[H][0] + (size_t)(T) * 64, (PA) + aD[H][0]);         \
    GLD16(aS[H][1] + (size_t)(T) * 64, (PA) + aD[H][1]);         \
  } while (0)
#define STG_B(PB, H, T) GLD16(bS[H] + (size_t)(T) * 64, (PB) + bD[H])
#define RD_A(PA, MH)                                                          \
  do {                                                                        \
    _Pragma("unroll") for (int mq = 0; mq < 4; ++mq) {                        \
      a[mq][0] = *(const short8*)&(PA)[aR + (MH)*4096 + mq * 1024 + sks0];    \
      a[mq][1] = *(const short8*)&(PA)[aR + (MH)*4096 + mq * 1024 + sks1];    \
    }                                                                         \
  } while (0)
#define RD_B(PB)                                                   \
  do {                                                             \
    _Pragma("unroll") for (int nq = 0; nq < 2; ++nq) {             \
      b[nq][0] = *(const short8*)&(PB)[bR + nq * 1024 + sks0];     \
      b[nq][1] = *(const short8*)&(PB)[bR + nq * 1024 + sks1];     \
    }                                                              \
  } while (0)
#define MFMA16(MH)                                                            \
  do {                                                                        \
    __builtin_amdgcn_s_setprio(1);                                            \
    _Pragma("unroll") for (int mq = 0; mq < 4; ++mq)                          \
        _Pragma("unroll") for (int nq = 0; nq < 2; ++nq) {                    \
      acc[(MH)*4 + mq][nq] = __builtin_amdgcn_mfma_f32_16x16x32_bf16(         \
          a[mq][0], b[nq][0], acc[(MH)*4 + mq][nq], 0, 0, 0);                 \
      acc[(MH)*4 + mq][nq] = __builtin_amdgcn_mfma_f32_16x16x32_bf16(         \
          a[mq][1], b[nq][1], acc[(MH)*4 + mq][nq], 0, 0, 0);                 \
    }                                                                         \
    __builtin_amdgcn_s_setprio(0);                                            \
  } while (0)

  // prologue: tiles 0 and 1 fully staged (12 loads in flight)
  STG_A(pa0, 0, 0); STG_B(pb0, 0, 0); STG_A(pa0, 1, 0); STG_B(pb0, 1, 0);
  STG_A(pa1, 0, 1); STG_B(pb1, 0, 1); STG_A(pa1, 1, 1); STG_B(pb1, 1, 1);
  VMCNT6();  // drain tile 0's 6; tile 1's 6 stay in flight
  BAR();

  const int NT = K >> 6;  // K/64 tiles, NT >= 16 here
  for (int t = 0; t < NT - 2; ++t) {
    // subA: compute tile t cluster 0; stage tile t+2 half 0
    RD_A(pa0, 0); RD_B(pb0);
    STG_A(pa2, 0, t + 2); STG_B(pb2, 0, t + 2);
    BAR();
    MFMA16(0);
    BAR();
    // subB: compute tile t cluster 1; stage tile t+2 half 1
    RD_A(pa0, 1);
    STG_A(pa2, 1, t + 2); STG_B(pb2, 1, t + 2);
    VMCNT6();  // drain tile t+1's 6 loads; tile t+2's 6 stay in flight
    BAR();
    MFMA16(1);
    BAR();
    // rotate buffers
    short* q;
    q = pa0; pa0 = pa1; pa1 = pa2; pa2 = q;
    q = pb0; pb0 = pb1; pb1 = pb2; pb2 = q;
  }
  // tile NT-2 (in pa0/pb0): complete per last loop VMCNT6; no staging
  RD_A(pa0, 0); RD_B(pb0);
  BAR(); MFMA16(0); BAR();
  RD_A(pa0, 1);
  VMCNT0();  // drain tile NT-1's 6 loads
  BAR(); MFMA16(1); BAR();
  // tile NT-1 (in pa1/pb1)
  RD_A(pa1, 0); RD_B(pb1);
  BAR(); MFMA16(0); BAR();
  RD_A(pa1, 1);
  BAR(); MFMA16(1);

  // epilogue
#pragma unroll
  for (int m = 0; m < 8; ++m) {
#pragma unroll
    for (int n = 0; n < 2; ++n) {
#pragma unroll
      for (int r = 0; r < 4; ++r) {
        float v = acc[m][n][r];
        int gr = brow + wr * 128 + m * 16 + kg * 4 + r;
        int gc = bcol + wc * 32 + n * 16 + lrow;
        if constexpr (MODE == 2) {
          int idx = gc - gr + (ml - 1);
          idx = min(max(idx, 0), 2 * ml - 2);
          ((float*)C0 + (size_t)z * cZ)[(size_t)gr * N + gc] =
              v * scale + rel_bias[idx];
        } else if constexpr (MODE == 3) {
          ((float*)C0 + (size_t)z * cZ)[(size_t)gr * N + gc] = v;
        } else {  // MODE 4: fused QKV, E=1024 slices
          int s = gc >> 10, cc = gc & 1023;
          if (s == 0) {
            ((short*)C0)[(size_t)gr * 1024 + cc] = f2bf(v);
          } else if (s == 1) {
            ((short*)C1)[(size_t)gr * 1024 + cc] = f2bf(v);
          } else {
            int b_ = gr / Cdim, c_ = gr % Cdim;
            ((short*)C2)[((size_t)b_ * 1024 + cc) * Cdim + c_] = f2bf(v);
          }
        }
      }
    }
  }
#undef STG_A
#undef STG_B
#undef RD_A
#undef RD_B
#undef MFMA16
}

// Row softmax in place (rows of 2048) + bf16 copy for the PV GEMM.
__global__ __launch_bounds__(256) void softmax_rows(float* __restrict__ w,
                                                    short* __restrict__ wb, int Cd) {
  const size_t row = blockIdx.x;
  float4* p = (float4*)(w + row * (size_t)Cd);
  const int tid = threadIdx.x;
  float4 v0 = p[tid];
  float4 v1 = p[tid + 256];
  float mx = fmaxf(fmaxf(fmaxf(v0.x, v0.y), fmaxf(v0.z, v0.w)),
                   fmaxf(fmaxf(v1.x, v1.y), fmaxf(v1.z, v1.w)));
#pragma unroll
  for (int o = 32; o; o >>= 1) mx = fmaxf(mx, __shfl_xor(mx, o));
  __shared__ float red[8];
  const int wv = tid >> 6;
  if ((tid & 63) == 0) red[wv] = mx;
  __syncthreads();
  mx = fmaxf(fmaxf(red[0], red[1]), fmaxf(red[2], red[3]));
  v0.x = __expf(v0.x - mx); v0.y = __expf(v0.y - mx);
  v0.z = __expf(v0.z - mx); v0.w = __expf(v0.w - mx);
  v1.x = __expf(v1.x - mx); v1.y = __expf(v1.y - mx);
  v1.z = __expf(v1.z - mx); v1.w = __expf(v1.w - mx);
  float s = v0.x + v0.y + v0.z + v0.w + v1.x + v1.y + v1.z + v1.w;
#pragma unroll
  for (int o = 32; o; o >>= 1) s += __shfl_xor(s, o);
  if ((tid & 63) == 0) red[4 + wv] = s;
  __syncthreads();
  s = red[4] + red[5] + red[6] + red[7];
  float inv = 1.0f / s;
  v0.x *= inv; v0.y *= inv; v0.z *= inv; v0.w *= inv;
  v1.x *= inv; v1.y *= inv; v1.z *= inv; v1.w *= inv;
  p[tid] = v0;
  p[tid + 256] = v1;
  short4v b0, b1;
  b0[0] = f2bf(v0.x); b0[1] = f2bf(v0.y); b0[2] = f2bf(v0.z); b0[3] = f2bf(v0.w);
  b1[0] = f2bf(v1.x); b1[1] = f2bf(v1.y); b1[2] = f2bf(v1.z); b1[3] = f2bf(v1.w);
  short* wrow = wb + row * (size_t)Cd;
  *(short4v*)&wrow[tid * 4] = b0;
  *(short4v*)&wrow[1024 + tid * 4] = b1;
}

extern "C" void kernel_launch(void* const* d_in, const int* in_sizes, int n_in,
                              void* d_out, int out_size, void* d_ws, size_t ws_size,
                              hipStream_t stream) {
  const float* x = (const float*)d_in[0];
  const float* Wq = (const float*)d_in[1];
  const float* Wk = (const float*)d_in[2];
  const float* Wv = (const float*)d_in[3];
  const float* rb = (const float*)d_in[4];

  const int E = 1024;
  const int Mt = in_sizes[0] / E;           // B*C = 8192
  const int Cd = out_size / Mt - E;         // 2048
  const int B = Mt / Cd;                    // 4
  const int ml = (in_sizes[4] + 1) / 2;     // max_len = 2048
  const float scale = 1.0f / sqrtf((float)E);

  // workspace layout (bf16 = short)
  short* xb = (short*)d_ws;                 // Mt*E
  short* wqb = xb + (size_t)Mt * E;         // E*E (Wq,Wk,Wv contiguous = 3072xE)
  short* wkb = wqb + (size_t)E * E;
  short* wvb = wkb + (size_t)E * E;
  short* Qb = wvb + (size_t)E * E;          // Mt*E
  short* Kb = Qb + (size_t)Mt * E;          // Mt*E
  short* Vt = Kb + (size_t)Mt * E;          // B*E*Cd
  short* wbf = Qb;                          // Mt*Cd (reuse Q+K after scores)

  float* outp = (float*)d_out;              // Mt*E
  float* wts = outp + (size_t)Mt * E;       // Mt*Cd

  cvt_f32_bf16<<<(Mt * E) / 2048, 256, 0, stream>>>(x, xb, (Mt * E) / 8);
  cvt_f32_bf16<<<(E * E) / 2048, 256, 0, stream>>>(Wq, wqb, (E * E) / 8);
  cvt_f32_bf16<<<(E * E) / 2048, 256, 0, stream>>>(Wk, wkb, (E * E) / 8);
  cvt_f32_bf16<<<(E * E) / 2048, 256, 0, stream>>>(Wv, wvb, (E * E) / 8);

  dim3 blk(512);
  // fused QKV projection: A = xb (8192x1024), Bt = [Wq;Wk;Wv] (3072x1024)
  gemm3b<4><<<dim3(Mt / 256, 3 * E / 128, 1), blk, 0, stream>>>(
      xb, wqb, Qb, Kb, Vt, nullptr, 3 * E, E, 0, 0, 0, Cd, 0.f, ml);
  // scores = Q K^T * scale + bias (fp32 into weights region)
  gemm3b<2><<<dim3(Cd / 256, Cd / 128, B), blk, 0, stream>>>(
      Qb, Kb, wts, nullptr, nullptr, rb, Cd, E, (long)Cd * E, (long)Cd * E,
      (long)Cd * Cd, Cd, scale, ml);
  softmax_rows<<<Mt, 256, 0, stream>>>(wts, wbf, Cd);
  // out = weights @ V (A = bf16 weights, Bt = V^T)
  gemm3b<3><<<dim3(Cd / 256, E / 128, B), blk, 0, stream>>>(
      wbf, Vt, outp, nullptr, nullptr, nullptr, E, Cd, (long)Cd * Cd,
      (long)E * Cd, (long)Cd * E, Cd, 0.f, ml);
}